// Round 5
// baseline (222.939 us; speedup 1.0000x reference)
//
#include <hip/hip_runtime.h>

// conv2d 3x3 s1 p1, NCHW fp32, N=16 C=K=64 H=W=224. Implicit GEMM bf16 MFMA 32x32x16.
// wprep: wgt fp32 [64][64][3][3] -> bf16 K-major [36 ks][2 g][64 oc][8 c] in d_ws.
// conv: 448 blocks x 256 thr (4 waves = 2 oc-halves x 2 row-groups), 4 rows/wave,
//   8 output rows/iter, 7 iters per 56-row chunk. 18-slot LDS ring (76.5 KB, 2 blk/CU).
//   Depth-4 staging pipeline: rows h+9..h+12 issued at iter top (float2 loads),
//   rows h+13..h+16 issued as earlier rows are written; cvt+ds_write_b64 under MFMA.
//   Halo: one (slot,row) per thread, issued at top. dh2 weights streamed from L2,
//   stream loads issued BEFORE subsequent pv loads (monotone vmcnt queue).

#define HH 224
#define WW 224
#define CHW (HH * WW)
#define PLANE 4352      // 34 w * 64 c * 2 B
#define NSLOT 18

typedef short bf16x4 __attribute__((ext_vector_type(4)));
typedef short bf16x8 __attribute__((ext_vector_type(8)));
typedef float f32x16 __attribute__((ext_vector_type(16)));

__device__ __forceinline__ unsigned short f2bf(float f) {
    union { float f; unsigned int u; } v; v.f = f;
    unsigned int u = v.u;
    return (unsigned short)((u + 0x7fffu + ((u >> 16) & 1u)) >> 16);  // RNE
}

#define SGB  __builtin_amdgcn_sched_group_barrier
#define MFMA __builtin_amdgcn_mfma_f32_32x32x16_bf16

__global__ void wprep_kernel(const float* __restrict__ wgt, unsigned short* __restrict__ wb) {
    const int i = blockIdx.x * 256 + threadIdx.x;
    if (i >= 36864) return;
    const int j   = i & 7;
    const int oc  = (i >> 3) & 63;
    const int g   = (i >> 9) & 1;
    const int ks  = i >> 10;
    const int tap = ks >> 2;
    const int c   = (ks & 3) * 16 + g * 8 + j;
    wb[i] = f2bf(wgt[(oc * 64 + c) * 9 + tap]);
}

// 6 ds_read_b128 + 12 MFMA (4 rows x 3 dh) for one (dw, cq); all indices literal.
#define MMA_CQ(dw, cq, WFU) do {                                              \
    const int off_ = (((cq) * 32 + g16) ^ swz_);                              \
    const bf16x8 B0 = *(const bf16x8*)(ldsB + sl0 + wb_ + off_);              \
    const bf16x8 B1 = *(const bf16x8*)(ldsB + sl1 + wb_ + off_);              \
    const bf16x8 B2 = *(const bf16x8*)(ldsB + sl2 + wb_ + off_);              \
    const bf16x8 B3 = *(const bf16x8*)(ldsB + sl3 + wb_ + off_);              \
    const bf16x8 B4 = *(const bf16x8*)(ldsB + sl4 + wb_ + off_);              \
    const bf16x8 B5 = *(const bf16x8*)(ldsB + sl5 + wb_ + off_);              \
    a0 = MFMA(wfrag[(dw)*4 + (cq)], B0, a0, 0, 0, 0);                         \
    a1 = MFMA(wfrag[(dw)*4 + (cq)], B1, a1, 0, 0, 0);                         \
    a2 = MFMA(wfrag[(dw)*4 + (cq)], B2, a2, 0, 0, 0);                         \
    a3 = MFMA(wfrag[(dw)*4 + (cq)], B3, a3, 0, 0, 0);                         \
    a0 = MFMA(wfrag[12 + (dw)*4 + (cq)], B1, a0, 0, 0, 0);                    \
    a1 = MFMA(wfrag[12 + (dw)*4 + (cq)], B2, a1, 0, 0, 0);                    \
    a2 = MFMA(wfrag[12 + (dw)*4 + (cq)], B3, a2, 0, 0, 0);                    \
    a3 = MFMA(wfrag[12 + (dw)*4 + (cq)], B4, a3, 0, 0, 0);                    \
    a0 = MFMA(WFU, B2, a0, 0, 0, 0);                                          \
    a1 = MFMA(WFU, B3, a1, 0, 0, 0);                                          \
    a2 = MFMA(WFU, B4, a2, 0, 0, 0);                                          \
    a3 = MFMA(WFU, B5, a3, 0, 0, 0);                                          \
    SGB(0x100, 6, 0); SGB(0x008, 12, 0);                                      \
} while (0)

// One section = 2 cq of one dw; first issues NEXT section's dh2 frags (ping-pong).
#define SECTION(dw, cqp, WFU0, WFU1, WFLD0, WFLD1, ldw, lcqp) do {            \
    WFLD0 = *(const bf16x8*)(wlane + ((6 + (ldw))*4 + 2*(lcqp)    ) * 1024);  \
    WFLD1 = *(const bf16x8*)(wlane + ((6 + (ldw))*4 + 2*(lcqp) + 1) * 1024);  \
    const int wl_  = s + (dw);                                                \
    const int swz_ = (wl_ & 7) << 4;                                          \
    const int wb_  = wl_ * 128;                                               \
    MMA_CQ(dw, 2*(cqp),     WFU0);                                            \
    MMA_CQ(dw, 2*(cqp) + 1, WFU1);                                            \
} while (0)

// Issue interior loads of row h+9+k into float2 P[4] (4 channels x w-pair).
#define STIS(k, P) do { if (st) {                                             \
    const int r_ = h + 9 + (k);                                               \
    const bool ok_ = (r_ < HH);                                               \
    _Pragma("unroll")                                                         \
    for (int i = 0; i < 4; ++i) {                                             \
        if (ok_) P[i] = *(const float2*)(pxm + i * CHW + r_ * WW);            \
        else { P[i].x = 0.f; P[i].y = 0.f; }                                  \
    } } } while (0)

// cvt + 2x ds_write_b64 of row h+9+k; halo owner thread writes its b64 too.
#define STWS(k, P) do { if (st) {                                             \
    int sw_ = slw + (k); if (sw_ >= NSLOT) sw_ -= NSLOT;                      \
    bf16x4 lo_, hi_;                                                          \
    _Pragma("unroll")                                                         \
    for (int i = 0; i < 4; ++i) {                                             \
        lo_[i] = (short)f2bf(P[i].x);                                         \
        hi_[i] = (short)f2bf(P[i].y);                                         \
    }                                                                         \
    *(bf16x4*)(ldsB + sw_ * PLANE + wA * 128 + (cg8 ^ swzA)) = lo_;           \
    *(bf16x4*)(ldsB + sw_ * PLANE + wB * 128 + (cg8 ^ swzB)) = hi_;           \
    if (hk == (k)) {                                                          \
        bf16x4 hh_;                                                           \
        _Pragma("unroll")                                                     \
        for (int i = 0; i < 4; ++i) hh_[i] = (short)f2bf(hv[i]);              \
        *(bf16x4*)(ldsB + sw_ * PLANE + hwl * 128 + (hcg8 ^ hswz)) = hh_;     \
    } } } while (0)

__global__ __launch_bounds__(256, 2)
void conv3x3_mfma(const float* __restrict__ x, const unsigned short* __restrict__ wb,
                  float* __restrict__ out) {
    __shared__ __align__(16) unsigned short lds[NSLOT * 34 * 64];  // 78336 B
    char* ldsB = (char*)lds;

    const int tid  = threadIdx.x;
    const int lane = tid & 63;
    const int wv   = tid >> 6;
    const int och  = wv & 1;   // oc half
    const int rg4  = wv >> 1;  // row group (4 rows each)
    const int s    = lane & 31;
    const int g    = lane >> 5;
    const int g16  = g * 16;

    const int bid = blockIdx.x;
    const int n   = bid / 28;
    const int rem = bid % 28;
    const int ws  = rem / 4;
    const int hc  = rem % 4;
    const int wbase = ws * 32;
    const int h0    = hc * 56;

    // ---- weights: dh0/dh1 resident (24 frags), dh2 ping-pong stream ----
    const unsigned short* wlane = wb + g * 512 + (och * 32 + s) * 8;
    bf16x8 wfrag[24];
#pragma unroll
    for (int ks = 0; ks < 24; ++ks)
        wfrag[ks] = *(const bf16x8*)(wlane + ks * 1024);
    bf16x8 wfA0 = *(const bf16x8*)(wlane + 24 * 1024);
    bf16x8 wfA1 = *(const bf16x8*)(wlane + 25 * 1024);
    bf16x8 wfB0 = {}, wfB1 = {};

    // ---- prologue: stage rows h0-1 .. h0+8 ----
    for (int p = tid; p < 10 * 272; p += 256) {
        const int rrel = p / 272;
        const int q  = p % 272;
        const int c8 = q / 34;
        const int wl = q % 34;
        const int r  = h0 - 1 + rrel;
        const int gw = wbase - 1 + wl;
        bf16x8 f = {};
        if (r >= 0 && r < HH && gw >= 0 && gw < WW) {
            const float* px = x + (n * 64 + c8 * 8) * CHW + r * WW + gw;
#pragma unroll
            for (int j = 0; j < 8; ++j) f[j] = (short)f2bf(px[j * CHW]);
        }
        *(bf16x8*)(ldsB + ((r + NSLOT) % NSLOT) * PLANE + wl * 128
                   + ((c8 * 16) ^ ((wl & 7) << 4))) = f;
    }

    // ---- interior staging coords: thread = (wp = tid&15, cg = tid>>4) ----
    const int wp  = tid & 15;
    const int cg  = tid >> 4;
    const int cg8 = cg * 8;
    const int wA  = 1 + 2 * wp;            // rel-w of .x
    const int wB  = 2 + 2 * wp;            // rel-w of .y
    const int swzA = (wA & 7) << 4;
    const int swzB = (wB & 7) << 4;
    const float* pxm = x + (n * 64 + 4 * cg) * CHW + (wbase + 2 * wp);

    // ---- halo: thread owns one (slot, row): hk = tid>>5, hs = tid&31 ----
    const int hk   = tid >> 5;
    const int hs   = tid & 31;
    const int hcg  = hs & 15;
    const int hcg8 = hcg * 8;
    const int hwl  = (hs >> 4) ? 33 : 0;
    const int hswz = (hwl & 7) << 4;
    const int ghw  = wbase - 1 + hwl;
    const bool hokw = (ghw >= 0 && ghw < WW);
    const float* pxh = x + (n * 64 + 4 * hcg) * CHW + ghw;

    __syncthreads();

#pragma unroll 1
    for (int it = 0; it < 7; ++it) {
        const int h  = h0 + 8 * it;
        const int hb = h + 4 * rg4;
        const bool st = (it < 6);
        const int slw = (h + 9) % NSLOT;

        int t_ = (hb - 1 + NSLOT) % NSLOT;
        const int sl0 = t_ * PLANE; t_ = (t_ + 1 == NSLOT) ? 0 : t_ + 1;
        const int sl1 = t_ * PLANE; t_ = (t_ + 1 == NSLOT) ? 0 : t_ + 1;
        const int sl2 = t_ * PLANE; t_ = (t_ + 1 == NSLOT) ? 0 : t_ + 1;
        const int sl3 = t_ * PLANE; t_ = (t_ + 1 == NSLOT) ? 0 : t_ + 1;
        const int sl4 = t_ * PLANE; t_ = (t_ + 1 == NSLOT) ? 0 : t_ + 1;
        const int sl5 = t_ * PLANE;

        float2 p0[4], p1[4], p2[4], p3[4];
        float hv[4];
        f32x16 a0 = {}, a1 = {}, a2 = {}, a3 = {};

        // depth-4 prefetch: rows h+9..h+12 + this thread's halo row, all issued now
        STIS(0, p0); STIS(1, p1); STIS(2, p2); STIS(3, p3);
        if (st) {
            const int rh_ = h + 9 + hk;
            const bool ok_ = (rh_ < HH) && hokw;
#pragma unroll
            for (int i = 0; i < 4; ++i) hv[i] = ok_ ? pxh[i * CHW + rh_ * WW] : 0.f;
        }
        __builtin_amdgcn_sched_barrier(0);

        SECTION(0, 0, wfA0, wfA1, wfB0, wfB1, 0, 1); STWS(0, p0); STIS(4, p0);
        SECTION(0, 1, wfB0, wfB1, wfA0, wfA1, 1, 0); STWS(1, p1); STIS(5, p1);
        SECTION(1, 0, wfA0, wfA1, wfB0, wfB1, 1, 1); STWS(2, p2); STIS(6, p2);
        SECTION(1, 1, wfB0, wfB1, wfA0, wfA1, 2, 0); STWS(3, p3); STIS(7, p3);
        SECTION(2, 0, wfA0, wfA1, wfB0, wfB1, 2, 1); STWS(4, p0);
        SECTION(2, 1, wfB0, wfB1, wfA0, wfA1, 0, 0); STWS(5, p1);

        // ---- C stores: rows hb..hb+3 (col = s = w; row = (rg&3)+8*(rg>>2)+4g = oc) ----
        float* po = out + (n * 64 + och * 32 + 4 * g) * CHW + hb * WW + wbase + s;
#pragma unroll
        for (int rg = 0; rg < 16; ++rg) {
            const int o_ = ((rg & 3) + 8 * (rg >> 2)) * CHW;
            po[o_]      = a0[rg];
            po[o_ + WW] = a1[rg];
        }
        STWS(6, p2);
#pragma unroll
        for (int rg = 0; rg < 16; ++rg) {
            const int o_ = ((rg & 3) + 8 * (rg >> 2)) * CHW;
            po[o_ + 2 * WW] = a2[rg];
            po[o_ + 3 * WW] = a3[rg];
        }
        STWS(7, p3);

        __syncthreads();  // rows h+9..h+16 visible for next iter
    }
}

extern "C" void kernel_launch(void* const* d_in, const int* in_sizes, int n_in,
                              void* d_out, int out_size, void* d_ws, size_t ws_size,
                              hipStream_t stream) {
    const float* x   = (const float*)d_in[0];
    const float* wgt = (const float*)d_in[1];
    float* out       = (float*)d_out;
    unsigned short* wbuf = (unsigned short*)d_ws;  // 73728 B needed

    wprep_kernel<<<dim3(144), dim3(256), 0, stream>>>(wgt, wbuf);
    conv3x3_mfma<<<dim3(448), dim3(256), 0, stream>>>(x, wbuf, out);
}